// Round 1
// baseline (151.667 us; speedup 1.0000x reference)
//
#include <hip/hip_runtime.h>

#define BATCH 2
#define N 1024
#define NBINS 22
#define TDIM 16
#define TSTR 20   // padded LDS table row stride in floats: 80 B (16B-aligned rows)
#define ROWS 2    // i-rows per block: amortizes the 16 KB j-staging + barrier

typedef float f32x4 __attribute__((ext_vector_type(4)));

__global__ __launch_bounds__(256) void te_enc(
    const float* __restrict__ coords,   // (B,N,3) f32
    const float* __restrict__ confp,    // (B,N)   f32
    const float* __restrict__ Wp,       // (22,16) f32
    const float* __restrict__ bp,       // (16)    f32
    const float* __restrict__ gp,       // (16)    f32
    const float* __restrict__ betap,    // (16)    f32
    float* __restrict__ out)            // (B,N,N,16) f32
{
    __shared__ __align__(16) float tbl[NBINS * TSTR];   // 1.76 KB
    __shared__ f32x4 ljc[N];                            // 16 KB: (x,y,z,conf) per j

    const int tid = threadIdx.x;
    const int blk = blockIdx.x;            // 0..1023 -> (batch, i0)
    const int batch = blk >> 9;            // 512 blocks per batch
    const int i0 = (blk & 511) * ROWS;

    const float* jc = coords + batch * N * 3;
    const float* jf = confp + batch * N;

    // Stage j-row (x,y,z,conf) into LDS as float4 (one b128 read per pair later).
    #pragma unroll
    for (int q = 0; q < 4; ++q) {
        const int j = tid + q * 256;
        f32x4 v;
        v.x = jc[j * 3 + 0];
        v.y = jc[j * 3 + 1];
        v.z = jc[j * 3 + 2];
        v.w = jf[j];
        ljc[j] = v;
    }

    // Precompute per-bin Linear+LayerNorm+ReLU rows (one thread per bin).
    // one_hot @ W selects row `bin` of W, so the MLP head collapses to 22x16.
    if (tid < NBINS) {
        float h[TDIM];
        float sum = 0.f;
        #pragma unroll
        for (int d = 0; d < TDIM; ++d) {
            h[d] = Wp[tid * TDIM + d] + bp[d];
            sum += h[d];
        }
        const float mu = sum * (1.f / TDIM);
        float s2 = 0.f;
        #pragma unroll
        for (int d = 0; d < TDIM; ++d) {
            const float t = h[d] - mu;
            s2 += t * t;
        }
        const float rs = 1.f / sqrtf(s2 * (1.f / TDIM) + 1e-5f);
        #pragma unroll
        for (int d = 0; d < TDIM; ++d) {
            const float v = (h[d] - mu) * rs * gp[d] + betap[d];
            tbl[tid * TSTR + d] = fmaxf(v, 0.f);
        }
    }
    __syncthreads();

    // Lane-major coalesced stores: lane l of wave w stores float4 index
    // j_base*4 + 64*c + l (1 KB/instruction). j = j_base + 16c + (l>>2),
    // sub = l&3; each j's bin computed redundantly by 4 lanes (cheap VALU).
    const int w   = tid >> 6;
    const int l   = tid & 63;
    const int lq  = l >> 2;
    const int sub = l & 3;
    const float EW = (float)(40.0 / 21.0);   // same edge expression as np.arange f32

    #pragma unroll 1   // do NOT unroll rows: keeps VGPR pressure flat
    for (int r = 0; r < ROWS; ++r) {
        const int i = i0 + r;
        const f32x4 pi = ljc[i];             // i-row coords/conf from LDS (same batch)
        const float xi = pi.x, yi = pi.y, zi = pi.z, ci = pi.w;
        const bool ci_ok = (ci > 0.f);

        f32x4* orow4 = (f32x4*)out + ((size_t)(batch * N + i)) * (N * TDIM / 4);

        #pragma unroll
        for (int it = 0; it < 4; ++it) {
            const int j_base = it * 256 + w * 64;
            #pragma unroll
            for (int c = 0; c < 4; ++c) {
                const int j = j_base + 16 * c + lq;
                const f32x4 pj = ljc[j];

                // Exact-f32 distance, matching numpy op order; *_rn blocks contraction.
                const float dx = __fsub_rn(xi, pj.x);
                const float dy = __fsub_rn(yi, pj.y);
                const float dz = __fsub_rn(zi, pj.z);
                float s = __fmul_rn(dx, dx);
                s = __fadd_rn(s, __fmul_rn(dy, dy));
                s = __fadd_rn(s, __fmul_rn(dz, dz));
                s = __fadd_rn(s, 1e-8f);
                const float dist = __fsqrt_rn(s);

                // O(1) searchsorted(side='left'): estimate k0 = trunc(dist/EW), then
                // exact boundary compares at k0 and k0+1 against fl(k*EW) — identical
                // to the 20-compare scan (estimate error ~1e-5 << edge spacing 1.9).
                int k0 = (int)__fmul_rn(dist, 0.525f);
                k0 = k0 < 20 ? k0 : 20;
                const int c1 = (__fmul_rn((float)k0, EW) < dist) ? 1 : 0;
                const int c2 = (__fmul_rn((float)(k0 + 1), EW) < dist) ? 1 : 0;
                const int idx = k0 + c1 + c2;            // = 1 + #{k in [1,20]: e_k < dist}
                int bin = idx < 20 ? idx : 20;           // clip to NUM_BINS-2
                if (!(ci_ok && pj.w > 0.f)) bin = NBINS - 1;
                const float cm = fminf(ci, pj.w);

                const f32x4 rrow = *(const f32x4*)&tbl[bin * TSTR + sub * 4];
                const f32x4 o = rrow * cm;

                // Streaming output: never re-read -> nontemporal, keep L2 clean.
                __builtin_nontemporal_store(o, orow4 + j_base * 4 + 64 * c + l);
            }
        }
    }
}

extern "C" void kernel_launch(void* const* d_in, const int* in_sizes, int n_in,
                              void* d_out, int out_size, void* d_ws, size_t ws_size,
                              hipStream_t stream) {
    const float* coords = (const float*)d_in[0];
    const float* conf   = (const float*)d_in[1];
    const float* W      = (const float*)d_in[2];
    const float* b      = (const float*)d_in[3];
    const float* g      = (const float*)d_in[4];
    const float* beta   = (const float*)d_in[5];
    float* out          = (float*)d_out;

    te_enc<<<dim3(BATCH * N / ROWS), dim3(256), 0, stream>>>(coords, conf, W, b, g, beta, out);
}

// Round 2
// 145.779 us; speedup vs baseline: 1.0404x; 1.0404x over previous
//
#include <hip/hip_runtime.h>

#define BATCH 2
#define N 1024
#define NBINS 22
#define TDIM 16
#define TSTR 20   // padded LDS table row stride in floats: 80 B (16B-aligned rows)

typedef float f32x4 __attribute__((ext_vector_type(4)));

__global__ __launch_bounds__(256) void te_enc(
    const float* __restrict__ coords,   // (B,N,3) f32
    const float* __restrict__ confp,    // (B,N)   f32
    const float* __restrict__ Wp,       // (22,16) f32
    const float* __restrict__ bp,       // (16)    f32
    const float* __restrict__ gp,       // (16)    f32
    const float* __restrict__ betap,    // (16)    f32
    float* __restrict__ out)            // (B,N,N,16) f32
{
    // Phase-1 products: per-j table float-offset (bin*TSTR) and conf-min.
    __shared__ __align__(16) float tbl[NBINS * TSTR];   // 1.76 KB
    __shared__ int2 bc[N];                              // 8 KB: (off_floats, cm_bits)

    const int tid = threadIdx.x;
    const int blk = blockIdx.x;           // 0..2047 -> (batch, i)
    const int batch = blk >> 10;
    const int i = blk & (N - 1);

    // Precompute per-bin Linear+LayerNorm+ReLU rows (one thread per bin).
    // one_hot @ W selects row `bin` of W, so the MLP head collapses to 22x16.
    if (tid < NBINS) {
        float h[TDIM];
        float sum = 0.f;
        #pragma unroll
        for (int d = 0; d < TDIM; ++d) {
            h[d] = Wp[tid * TDIM + d] + bp[d];
            sum += h[d];
        }
        const float mu = sum * (1.f / TDIM);
        float s2 = 0.f;
        #pragma unroll
        for (int d = 0; d < TDIM; ++d) {
            const float t = h[d] - mu;
            s2 += t * t;
        }
        const float rs = 1.f / sqrtf(s2 * (1.f / TDIM) + 1e-5f);
        #pragma unroll
        for (int d = 0; d < TDIM; ++d) {
            const float v = (h[d] - mu) * rs * gp[d] + betap[d];
            tbl[tid * TSTR + d] = fmaxf(v, 0.f);
        }
    }

    // ---- Phase 1: all heavy math once per j (not once per 16 output floats).
    const float* jc = coords + batch * N * 3;
    const float* jf = confp + batch * N;

    const float xi = coords[(batch * N + i) * 3 + 0];
    const float yi = coords[(batch * N + i) * 3 + 1];
    const float zi = coords[(batch * N + i) * 3 + 2];
    const float ci = confp[batch * N + i];
    const bool ci_ok = (ci > 0.f);
    const float EW = (float)(40.0 / 21.0);   // same edge expression as np.arange f32

    #pragma unroll
    for (int q = 0; q < 4; ++q) {
        const int j = tid + q * 256;
        const float xj = jc[j * 3 + 0];
        const float yj = jc[j * 3 + 1];
        const float zj = jc[j * 3 + 2];
        const float cj = jf[j];

        // Exact-f32 distance, matching numpy op order; *_rn blocks contraction.
        const float dx = __fsub_rn(xi, xj);
        const float dy = __fsub_rn(yi, yj);
        const float dz = __fsub_rn(zi, zj);
        float s = __fmul_rn(dx, dx);
        s = __fadd_rn(s, __fmul_rn(dy, dy));
        s = __fadd_rn(s, __fmul_rn(dz, dz));
        s = __fadd_rn(s, 1e-8f);
        const float dist = __fsqrt_rn(s);

        // O(1) searchsorted(side='left'): estimate k0 = trunc(dist/EW), then
        // exact boundary compares at k0 and k0+1 against fl(k*EW) — identical
        // to the 20-compare scan (estimate error ~1e-5 << edge spacing 1.9).
        int k0 = (int)__fmul_rn(dist, 0.525f);
        k0 = k0 < 20 ? k0 : 20;
        const int c1 = (__fmul_rn((float)k0, EW) < dist) ? 1 : 0;
        const int c2 = (__fmul_rn((float)(k0 + 1), EW) < dist) ? 1 : 0;
        const int idx = k0 + c1 + c2;            // = 1 + #{k in [1,20]: e_k < dist}
        int bin = idx < 20 ? idx : 20;           // clip to NUM_BINS-2
        if (!(ci_ok && cj > 0.f)) bin = NBINS - 1;
        const float cm = fminf(ci, cj);

        int2 v;
        v.x = bin * TSTR;                 // float-index offset into tbl
        v.y = __float_as_int(cm);
        bc[j] = v;
    }
    __syncthreads();

    // ---- Phase 2: pure expansion stream (as fill-like as possible).
    // Lane-major coalesced stores: lane l of wave w stores float4 index
    // it*1024 + w*256 + 64*c + l (1 KB/instruction). j = it*256 + w*64 + 16c + (l>>2).
    const int w   = tid >> 6;
    const int l   = tid & 63;
    const int lq  = l >> 2;
    const int sub4 = (l & 3) * 4;         // float offset of this lane's quarter row

    f32x4* orow4 = (f32x4*)out + ((size_t)(batch * N + i)) * (N * TDIM / 4);

    #pragma unroll
    for (int it = 0; it < 4; ++it) {
        const int j_base = it * 256 + w * 64;
        #pragma unroll
        for (int c = 0; c < 4; ++c) {
            const int j = j_base + 16 * c + lq;
            const int2 v = bc[j];                       // ds_read_b64, 4-lane broadcast
            const float cm = __int_as_float(v.y);
            const f32x4 r = *(const f32x4*)&tbl[v.x + sub4];   // ds_read_b128 gather
            orow4[j_base * 4 + 64 * c + l] = r * cm;           // 1 KB/wave store
        }
    }
}

extern "C" void kernel_launch(void* const* d_in, const int* in_sizes, int n_in,
                              void* d_out, int out_size, void* d_ws, size_t ws_size,
                              hipStream_t stream) {
    const float* coords = (const float*)d_in[0];
    const float* conf   = (const float*)d_in[1];
    const float* W      = (const float*)d_in[2];
    const float* b      = (const float*)d_in[3];
    const float* g      = (const float*)d_in[4];
    const float* beta   = (const float*)d_in[5];
    float* out          = (float*)d_out;

    te_enc<<<dim3(BATCH * N), dim3(256), 0, stream>>>(coords, conf, W, b, g, beta, out);
}